// Round 8
// baseline (179.528 us; speedup 1.0000x reference)
//
#include <hip/hip_runtime.h>
#include <hip/hip_bf16.h>

// BEVFormerLite: project BEV grid into 6 cameras, bilinear-sample, average
// valid cams, 1x1 conv + BN + ReLU.
// B=4 N=6 C=256 fH=29 fW=50, BEV 200x200 (P=40000). Output (4,256,200,200) f32.
//
// Round 8: conv-before-bilinear via linearity.
//   out[o,p] = relu(s_o * (1/cnt) * sum_slots sum_corners w_i * G[tex_i, o] + b_o)
//   where G = ft @ W^T per texel (34800 texels only, vs 160000 BEV points).
//  k0 prep+transpose: feats -> ft (channel-last bf16); W->bf16; geometry; BN fold.
//  k1 gemm2: G[tex,o] (M=34816 N=256 K=256 MFMA GEMM, r1's proven tile shape).
//  k2 combine: per (b, 64-pt tile): project+compact slots in LDS, then
//     thread=o gathers G scalars (coalesced across o) and writes out.
//     ~18x less sampling FLOPs than the fused-sampling design; write-bound.

#define P_TOT  40000
#define FH     29
#define FW     50
#define NCAM   6
#define NTEX   34800          // B*N*FH*FW
#define NTEXP  34816          // padded to multiple of 64

typedef short bf16x8 __attribute__((ext_vector_type(8)));
typedef float f32x4  __attribute__((ext_vector_type(4)));

__device__ __forceinline__ float bf2f(unsigned short u) {
    union { unsigned int i; float f; } x; x.i = ((unsigned int)u) << 16; return x.f;
}
__device__ __forceinline__ unsigned short f2bf(float f) {
    union { float f; unsigned int i; } x; x.f = f;
    unsigned int i = x.i;
    return (unsigned short)((i + 0x7FFFu + ((i >> 16) & 1u)) >> 16);  // RNE
}

// ---------------- k0: transpose + W->bf16 + geometry + BN fold ----------------
__global__ __launch_bounds__(256) void prep_transpose_kernel(
        const float* __restrict__ feats, const float* __restrict__ K,
        const float* __restrict__ E, const float* __restrict__ convw,
        const float* __restrict__ convb, const float* __restrict__ gamma,
        const float* __restrict__ beta, const float* __restrict__ mean,
        const float* __restrict__ var, float* __restrict__ params,
        float* __restrict__ sb, unsigned short* __restrict__ wbf,
        unsigned short* __restrict__ ft) {
    __shared__ unsigned short tile[256][58];   // pad 50->58 (116B stride)
    int blk = blockIdx.x;
    int t   = threadIdx.x;
    if (blk < 256) {                           // W -> bf16 (65536 entries)
        int idx = blk * 256 + t;
        wbf[idx] = f2bf(convw[idx]);
    }
    if (blk == 696) {                          // geometry + BN fold
        int o = t;
        float rstd = rsqrtf(var[o] + 1e-5f);
        float s = gamma[o] * rstd;
        sb[o]       = s;
        sb[256 + o] = (convb[o] - mean[o]) * s + beta[o];
        if (o >= 24) return;
        const float* e = E + o * 16;
        const float* k = K + o * 9;
        float a00=e[0], a01=e[1], a02=e[2],  t0=e[3];
        float a10=e[4], a11=e[5], a12=e[6],  t1=e[7];
        float a20=e[8], a21=e[9], a22=e[10], t2=e[11];
        float c00 =  (a11*a22 - a12*a21);
        float c01 = -(a10*a22 - a12*a20);
        float c02 =  (a10*a21 - a11*a20);
        float det = a00*c00 + a01*c01 + a02*c02;
        float id = 1.0f / det;
        float i00 =  c00*id;
        float i01 = -(a01*a22 - a02*a21)*id;
        float i02 =  (a01*a12 - a02*a11)*id;
        float i10 =  c01*id;
        float i11 =  (a00*a22 - a02*a20)*id;
        float i12 = -(a00*a12 - a02*a10)*id;
        float i20 =  c02*id;
        float i21 = -(a00*a21 - a01*a20)*id;
        float i22 =  (a00*a11 - a01*a10)*id;
        float tp0 = -(i00*t0 + i01*t1 + i02*t2);
        float tp1 = -(i10*t0 + i11*t1 + i12*t2);
        float tp2 = -(i20*t0 + i21*t1 + i22*t2);
        float* q = params + o * 12;
        q[0] = k[0]*i00 + k[1]*i10 + k[2]*i20;
        q[1] = k[0]*i01 + k[1]*i11 + k[2]*i21;
        q[2] = k[0]*tp0 + k[1]*tp1 + k[2]*tp2;
        q[3] = k[3]*i00 + k[4]*i10 + k[5]*i20;
        q[4] = k[3]*i01 + k[4]*i11 + k[5]*i21;
        q[5] = k[3]*tp0 + k[4]*tp1 + k[5]*tp2;
        q[6] = k[6]*i00 + k[7]*i10 + k[8]*i20;
        q[7] = k[6]*i01 + k[7]*i11 + k[8]*i21;
        q[8] = k[6]*tp0 + k[7]*tp1 + k[8]*tp2;
        q[9]  = i20;
        q[10] = i21;
        q[11] = tp2;
        return;
    }
    // transpose one (bn,y) row: feats (bn,c,y,x) f32 -> ft (bn,y,x,c) bf16
    int bn = blk / FH, y = blk - bn * FH;
    const float* src = feats + (size_t)bn * 256 * FH * FW + y * FW;
    #pragma unroll
    for (int i = 0; i < 25; ++i) {             // float2 reads; pairs stay in-row (50 even)
        int flat = i * 512 + t * 2;
        int c = flat / 50;
        int x = flat - c * 50;
        float2 v = *(const float2*)(src + c * FH * FW + x);
        tile[c][x]     = f2bf(v.x);
        tile[c][x + 1] = f2bf(v.y);
    }
    __syncthreads();
    unsigned short* dst = ft + (size_t)blk * 50 * 256;
    #pragma unroll
    for (int i = 0; i < 25; ++i) {             // writes: fully coalesced u32
        int flat = i * 512 + t * 2;
        int x = flat >> 8;
        int c = flat & 255;
        unsigned int v = (unsigned int)tile[c][x] | ((unsigned int)tile[c + 1][x] << 16);
        *(unsigned int*)(dst + x * 256 + c) = v;
    }
}

// ---------------- k1: G[tex,o] = sum_c ft[tex,c] * W[o,c]  (MFMA GEMM) ----------------
__global__ __launch_bounds__(256) void gemm2_kernel(const unsigned short* __restrict__ ftm,
                                                    const unsigned short* __restrict__ wbf,
                                                    unsigned short* __restrict__ G) {
    __shared__ unsigned short Ft[64][40];   // tex rows (A operand), 32k + 8 pad
    __shared__ unsigned short Wo[64][40];   // o rows   (B operand)
    int texbase = blockIdx.x * 64;          // 544 tiles (covers 34816)
    int obase   = blockIdx.y * 64;          // 4
    int tid  = threadIdx.x;
    int lane = tid & 63;
    int wv   = tid >> 6;
    int lrow = tid >> 2;
    int lk   = (tid & 3) * 8;
    const unsigned short* fsrc = ftm + (size_t)(texbase + lrow) * 256 + lk;  // rows <34816, in-bounds
    const unsigned short* wsrc = wbf + (size_t)(obase + lrow) * 256 + lk;
    f32x4 acc[4];
    #pragma unroll
    for (int nf = 0; nf < 4; ++nf) acc[nf] = (f32x4){0.f, 0.f, 0.f, 0.f};
    int arow = wv * 16 + (lane & 15);
    int kq   = (lane >> 4) * 8;
    for (int kt = 0; kt < 8; ++kt) {
        *(uint4*)&Ft[lrow][lk] = *(const uint4*)(fsrc + kt * 32);
        *(uint4*)&Wo[lrow][lk] = *(const uint4*)(wsrc + kt * 32);
        __syncthreads();
        bf16x8 a = *(const bf16x8*)&Ft[arow][kq];
        #pragma unroll
        for (int nf = 0; nf < 4; ++nf) {
            bf16x8 bb = *(const bf16x8*)&Wo[nf * 16 + (lane & 15)][kq];
            acc[nf] = __builtin_amdgcn_mfma_f32_16x16x32_bf16(a, bb, acc[nf], 0, 0, 0);
        }
        __syncthreads();
    }
    // D[row=tex (A side)][col=o (B side)]
    #pragma unroll
    for (int nf = 0; nf < 4; ++nf) {
        int o = obase + nf * 16 + (lane & 15);
        #pragma unroll
        for (int r = 0; r < 4; ++r) {
            int tex = texbase + wv * 16 + (lane >> 4) * 4 + r;
            G[(size_t)tex * 256 + o] = f2bf(acc[nf][r]);
        }
    }
}

// ---------------- k2: combine -- gather G + scale + bias + relu ----------------
__global__ __launch_bounds__(256) void combine_kernel(const float* __restrict__ params,
                                                      const unsigned short* __restrict__ G,
                                                      const float* __restrict__ sb,
                                                      float* __restrict__ out) {
    __shared__ int    sbase[64][6];          // texel*256 | okx | oky ; -1 = invalid
    __shared__ float4 swt[64][6];            // 4 bilinear weights (flag-zeroed)
    __shared__ int    scnt[64];
    __shared__ float  sscale[64];

    int tid   = threadIdx.x;
    int pbase = blockIdx.x * 64;
    int b     = blockIdx.y;

    // ---- phase A: projection, 384 (point,cam) tasks over 256 threads ----
    for (int task = tid; task < 384; task += 256) {
        int pt  = task / 6;
        int cam = task - pt * 6;
        int p   = pbase + pt;
        float gx = -49.75f + 0.5f * (float)(p % 200);
        float gy = -49.75f + 0.5f * (float)(p / 200);
        const float* q = params + (b * NCAM + cam) * 12;
        float wh    = q[6] * gx + q[7]  * gy + q[8];
        float depth = q[9] * gx + q[10] * gy + q[11];
        float inv = 1.0f / (wh + 1e-6f);
        float u = (q[0] * gx + q[1] * gy + q[2]) * inv;
        float v = (q[3] * gx + q[4] * gy + q[5]) * inv;
        float un = u * (50.0f / 1600.0f) * (2.0f / 49.0f) - 1.0f;
        float vn = v * (29.0f / 928.0f)  * (2.0f / 28.0f) - 1.0f;
        int bfv = -1;
        float4 w4 = {0.f, 0.f, 0.f, 0.f};
        if (depth > 0.1f && un >= -1.0f && un <= 1.0f &&
                            vn >= -1.0f && vn <= 1.0f) {
            float xs = (un + 1.0f) * 0.5f * 49.0f;
            float ys = (vn + 1.0f) * 0.5f * 28.0f;
            float x0f = floorf(xs), y0f = floorf(ys);
            float wx = xs - x0f, wy = ys - y0f;
            int x0 = (int)x0f, y0 = (int)y0f;
            int okx = (x0 < FW - 1) ? 1 : 0;
            int oky = (y0 < FH - 1) ? 2 : 0;
            int base = (((b * NCAM + cam) * FH + y0) * FW + x0) * 256;  // low 8 bits free
            bfv = base | okx | oky;
            float iwx = 1.0f - wx, iwy = 1.0f - wy;
            w4.x = iwx * iwy;
            w4.y = okx ? wx * iwy : 0.0f;
            w4.z = oky ? iwx * wy : 0.0f;
            w4.w = (okx && oky) ? wx * wy : 0.0f;
        }
        sbase[pt][cam] = bfv;
        swt[pt][cam]   = w4;
    }
    __syncthreads();

    // ---- compact slots per point ----
    if (tid < 64) {
        int c = 0;
        #pragma unroll
        for (int cam = 0; cam < NCAM; ++cam) {
            int v = sbase[tid][cam];
            float4 w = swt[tid][cam];
            if (v >= 0) { sbase[tid][c] = v; swt[tid][c] = w; ++c; }
        }
        scnt[tid]   = c;
        sscale[tid] = 1.0f / ((float)c + 1e-6f);
    }
    __syncthreads();

    // ---- main: thread = output channel o; gather G (coalesced across o) ----
    int o = tid;
    float so = sb[o];
    float bo = sb[256 + o];
    const unsigned short* Go = G + o;
    float* op = out + ((size_t)(b * 256 + o)) * P_TOT + pbase;
    for (int pg = 0; pg < 16; ++pg) {
        float4 vout;
        #pragma unroll
        for (int j = 0; j < 4; ++j) {
            int p = pg * 4 + j;
            int n = scnt[p];                       // wave-uniform
            float a = 0.f;
            for (int s = 0; s < n; ++s) {
                int bfv  = sbase[p][s];            // broadcast
                float4 w = swt[p][s];
                const unsigned short* g0 = Go + (bfv & ~255);
                int o01 = (bfv & 1) ? 256 : 0;
                int o10 = (bfv & 2) ? FW * 256 : 0;
                a += w.x * bf2f(g0[0])
                   + w.y * bf2f(g0[o01])
                   + w.z * bf2f(g0[o10])
                   + w.w * bf2f(g0[o10 + o01]);
            }
            ((float*)&vout)[j] = fmaxf(a * sscale[p] * so + bo, 0.0f);
        }
        *(float4*)(op + pg * 4) = vout;
    }
}

extern "C" void kernel_launch(void* const* d_in, const int* in_sizes, int n_in,
                              void* d_out, int out_size, void* d_ws, size_t ws_size,
                              hipStream_t stream) {
    const float* feats = (const float*)d_in[0];
    const float* intr  = (const float*)d_in[1];
    const float* extr  = (const float*)d_in[2];
    const float* convw = (const float*)d_in[3];
    const float* convb = (const float*)d_in[4];
    const float* gamma = (const float*)d_in[5];
    const float* beta  = (const float*)d_in[6];
    const float* mean  = (const float*)d_in[7];
    const float* var   = (const float*)d_in[8];

    char* ws = (char*)d_ws;
    float*          params = (float*)(ws + 0);               // 1152 B
    float*          sb     = (float*)(ws + 2048);            // 2 KB
    unsigned short* wbf    = (unsigned short*)(ws + 4096);   // 128 KB
    unsigned short* ft     = (unsigned short*)(ws + 135168); // 34816*512 = 17.83 MB
    unsigned short* G      = (unsigned short*)(ws + 135168 + (size_t)NTEXP * 512); // 17.83 MB
    float* out = (float*)d_out;

    hipLaunchKernelGGL(prep_transpose_kernel, dim3(697), dim3(256), 0, stream,
                       feats, intr, extr, convw, convb, gamma, beta, mean, var,
                       params, sb, wbf, ft);
    hipLaunchKernelGGL(gemm2_kernel, dim3(NTEXP / 64, 4), dim3(256), 0, stream,
                       ft, wbf, G);
    hipLaunchKernelGGL(combine_kernel, dim3(625, 4), dim3(256), 0, stream,
                       params, G, sb, out);
}

// Round 9
// 115.337 us; speedup vs baseline: 1.5566x; 1.5566x over previous
//
#include <hip/hip_runtime.h>
#include <hip/hip_bf16.h>

// BEVFormerLite fused: project BEV grid into 6 cameras, bilinear-sample,
// average valid cams, 1x1 conv + BN + ReLU.
// B=4 N=6 C=256 fH=29 fW=50, BEV 200x200 (P=40000). Output (4,256,200,200) f32.
//
// Round 9 = r7 pipeline, gather restructured for memory-level parallelism.
//  k0 prep+transpose (merged, unchanged).
//  k1 fused: 512 threads / 32 points (grid 1250 x 4, 5000 blocks, ~4/CU).
//     phase A: projection -> compacted 8B slots (LDS).
//     phase B: 16 threads/point = (x-side cp) x (channel-eighth e); each
//              thread: 2 corners x 32 ch = 8 INDEPENDENT 16B loads per slot
//              (vs 16 from one thread in r7) -> one latency-wait per slot;
//              corner-pair reduce via single shfl_xor(8).
//     phase C: K=256 MFMA GEMM (2 o-tiles x 2 p-tiles per wave), A direct
//              from L2-resident W, no k-loop barriers; BN+ReLU epilogue.

#define P_TOT  40000
#define FH     29
#define FW     50
#define NCAM   6

typedef short bf16x8 __attribute__((ext_vector_type(8)));
typedef float f32x4  __attribute__((ext_vector_type(4)));
typedef unsigned short u16x8 __attribute__((ext_vector_type(8)));

__device__ __forceinline__ float bf2f(unsigned short u) {
    union { unsigned int i; float f; } x; x.i = ((unsigned int)u) << 16; return x.f;
}
__device__ __forceinline__ unsigned short f2bf(float f) {
    union { float f; unsigned int i; } x; x.f = f;
    unsigned int i = x.i;
    return (unsigned short)((i + 0x7FFFu + ((i >> 16) & 1u)) >> 16);  // RNE
}

// ---------------- k0: transpose + W->bf16 + geometry + BN fold ----------------
__global__ __launch_bounds__(256) void prep_transpose_kernel(
        const float* __restrict__ feats, const float* __restrict__ K,
        const float* __restrict__ E, const float* __restrict__ convw,
        const float* __restrict__ convb, const float* __restrict__ gamma,
        const float* __restrict__ beta, const float* __restrict__ mean,
        const float* __restrict__ var, float* __restrict__ params,
        float* __restrict__ sb, unsigned short* __restrict__ wbf,
        unsigned short* __restrict__ ft) {
    __shared__ unsigned short tile[256][58];   // pad 50->58 (116B stride)
    int blk = blockIdx.x;
    int t   = threadIdx.x;
    if (blk < 256) {                           // W -> bf16 (65536 entries)
        int idx = blk * 256 + t;
        wbf[idx] = f2bf(convw[idx]);
    }
    if (blk == 696) {                          // geometry + BN fold
        int o = t;
        float rstd = rsqrtf(var[o] + 1e-5f);
        float s = gamma[o] * rstd;
        sb[o]       = s;
        sb[256 + o] = (convb[o] - mean[o]) * s + beta[o];
        if (o >= 24) return;
        const float* e = E + o * 16;
        const float* k = K + o * 9;
        float a00=e[0], a01=e[1], a02=e[2],  t0=e[3];
        float a10=e[4], a11=e[5], a12=e[6],  t1=e[7];
        float a20=e[8], a21=e[9], a22=e[10], t2=e[11];
        float c00 =  (a11*a22 - a12*a21);
        float c01 = -(a10*a22 - a12*a20);
        float c02 =  (a10*a21 - a11*a20);
        float det = a00*c00 + a01*c01 + a02*c02;
        float id = 1.0f / det;
        float i00 =  c00*id;
        float i01 = -(a01*a22 - a02*a21)*id;
        float i02 =  (a01*a12 - a02*a11)*id;
        float i10 =  c01*id;
        float i11 =  (a00*a22 - a02*a20)*id;
        float i12 = -(a00*a12 - a02*a10)*id;
        float i20 =  c02*id;
        float i21 = -(a00*a21 - a01*a20)*id;
        float i22 =  (a00*a11 - a01*a10)*id;
        float tp0 = -(i00*t0 + i01*t1 + i02*t2);
        float tp1 = -(i10*t0 + i11*t1 + i12*t2);
        float tp2 = -(i20*t0 + i21*t1 + i22*t2);
        float* q = params + o * 12;
        q[0] = k[0]*i00 + k[1]*i10 + k[2]*i20;
        q[1] = k[0]*i01 + k[1]*i11 + k[2]*i21;
        q[2] = k[0]*tp0 + k[1]*tp1 + k[2]*tp2;
        q[3] = k[3]*i00 + k[4]*i10 + k[5]*i20;
        q[4] = k[3]*i01 + k[4]*i11 + k[5]*i21;
        q[5] = k[3]*tp0 + k[4]*tp1 + k[5]*tp2;
        q[6] = k[6]*i00 + k[7]*i10 + k[8]*i20;
        q[7] = k[6]*i01 + k[7]*i11 + k[8]*i21;
        q[8] = k[6]*tp0 + k[7]*tp1 + k[8]*tp2;
        q[9]  = i20;
        q[10] = i21;
        q[11] = tp2;
        return;
    }
    // transpose one (bn,y) row: feats (bn,c,y,x) f32 -> ft (bn,y,x,c) bf16
    int bn = blk / FH, y = blk - bn * FH;
    const float* src = feats + (size_t)bn * 256 * FH * FW + y * FW;
    #pragma unroll
    for (int i = 0; i < 25; ++i) {             // float2 reads; pairs stay in-row (50 even)
        int flat = i * 512 + t * 2;
        int c = flat / 50;
        int x = flat - c * 50;
        float2 v = *(const float2*)(src + c * FH * FW + x);
        tile[c][x]     = f2bf(v.x);
        tile[c][x + 1] = f2bf(v.y);
    }
    __syncthreads();
    unsigned short* dst = ft + (size_t)blk * 50 * 256;
    #pragma unroll
    for (int i = 0; i < 25; ++i) {             // writes: fully coalesced u32
        int flat = i * 512 + t * 2;
        int x = flat >> 8;
        int c = flat & 255;
        unsigned int v = (unsigned int)tile[c][x] | ((unsigned int)tile[c + 1][x] << 16);
        *(unsigned int*)(dst + x * 256 + c) = v;
    }
}

// ---------------- k1: fused sample + GEMM + BN + ReLU ----------------
__global__ __launch_bounds__(512, 4) void fused_kernel(const unsigned short* __restrict__ ft,
                                                       const float* __restrict__ params,
                                                       const unsigned short* __restrict__ wbf,
                                                       const float* __restrict__ sb,
                                                       float* __restrict__ out) {
    __shared__ unsigned short Bt[32][264];        // bev tile [p][c], 528B rows
    __shared__ int           sbf[32][6];          // slot: base|okx|oky, -1 = invalid
    __shared__ unsigned int  swxy[32][6];         // wx,wy as u16 fixed-point
    __shared__ int           scnt[32];
    __shared__ float         sscale[32];
    __shared__ float         ssb[512];            // scale[256] + bias[256]

    int tid   = threadIdx.x;
    int pbase = blockIdx.x * 32;
    int b     = blockIdx.y;

    ssb[tid] = sb[tid];

    // ---- phase A: projection, one thread per (point, cam) ----
    if (tid < 192) {
        int pt  = tid / 6;
        int cam = tid - pt * 6;
        int p   = pbase + pt;
        float gx = -49.75f + 0.5f * (float)(p % 200);
        float gy = -49.75f + 0.5f * (float)(p / 200);
        const float* q = params + (b * NCAM + cam) * 12;
        float wh    = q[6] * gx + q[7]  * gy + q[8];
        float depth = q[9] * gx + q[10] * gy + q[11];
        float inv = 1.0f / (wh + 1e-6f);
        float u = (q[0] * gx + q[1] * gy + q[2]) * inv;
        float v = (q[3] * gx + q[4] * gy + q[5]) * inv;
        float un = u * (50.0f / 1600.0f) * (2.0f / 49.0f) - 1.0f;
        float vn = v * (29.0f / 928.0f)  * (2.0f / 28.0f) - 1.0f;
        int bfv = -1; unsigned int wxy = 0;
        if (depth > 0.1f && un >= -1.0f && un <= 1.0f &&
                            vn >= -1.0f && vn <= 1.0f) {
            float xs = (un + 1.0f) * 0.5f * 49.0f;
            float ys = (vn + 1.0f) * 0.5f * 28.0f;
            float x0f = floorf(xs), y0f = floorf(ys);
            float wx = xs - x0f, wy = ys - y0f;
            int x0 = (int)x0f, y0 = (int)y0f;
            int okx = (x0 < FW - 1) ? 1 : 0;
            int oky = (y0 < FH - 1) ? 2 : 0;
            int base = (((b * NCAM + cam) * FH + y0) * FW + x0) * 256; // low 8 bits free
            bfv = base | okx | oky;
            wxy = (unsigned int)(wx * 65535.0f + 0.5f)
                | ((unsigned int)(wy * 65535.0f + 0.5f) << 16);
        }
        sbf[pt][cam]  = bfv;
        swxy[pt][cam] = wxy;
    }
    __syncthreads();

    // ---- compact slots per point (cam order preserved) ----
    if (tid < 32) {
        int c = 0;
        #pragma unroll
        for (int cam = 0; cam < NCAM; ++cam) {
            int v = sbf[tid][cam];
            unsigned int w = swxy[tid][cam];
            if (v >= 0) { sbf[tid][c] = v; swxy[tid][c] = w; ++c; }
        }
        scnt[tid]   = c;
        sscale[tid] = 1.0f / ((float)c + 1e-6f);
    }
    __syncthreads();

    // ---- phase B: 16 threads/point = (x-side cp) x (eighth e); 2 corners x 32ch each ----
    // Thread loads 8 INDEPENDENT 16B vectors per slot (4 qv x 2 y-corners) ->
    // one L2/L3 latency-wait per slot instead of a serial chain.
    {
        int pt = tid >> 4;              // 0..31
        int sub = tid & 15;
        int cp  = sub >> 3;             // x-side: 0 = left (iwx), 1 = right (wx)
        int e   = sub & 7;              // channel eighth; chunks at e*8 + qv*64
        int chb = e * 8;
        float acc[32];
        #pragma unroll
        for (int j = 0; j < 32; ++j) acc[j] = 0.0f;
        int n = scnt[pt];
        float sc = sscale[pt];
        for (int s = 0; s < n; ++s) {
            int bfv = sbf[pt][s];
            unsigned int wxy = swxy[pt][s];
            int base = bfv & ~255;
            int okx = bfv & 1, oky = bfv & 2;
            float wx = (float)(wxy & 0xffffu) * (1.0f / 65535.0f);
            float wy = (float)(wxy >> 16)     * (1.0f / 65535.0f);
            float wxs = cp ? wx : (1.0f - wx);
            if (cp && !okx) wxs = 0.0f;
            float iwy = 1.0f - wy;
            float w0 = wxs * iwy;                     // y0 corner
            float w1 = oky ? wxs * wy : 0.0f;         // y1 corner
            int xoff = (cp && okx) ? 256 : 0;
            int yoff = oky ? FW * 256 : 0;
            const unsigned short* pA = ft + base + xoff + chb;
            #pragma unroll
            for (int qv = 0; qv < 4; ++qv) {
                u16x8 v0 = *(const u16x8*)(pA + qv * 64);
                u16x8 v1 = *(const u16x8*)(pA + yoff + qv * 64);
                #pragma unroll
                for (int j = 0; j < 8; ++j)
                    acc[qv * 8 + j] += w0 * bf2f(v0[j]) + w1 * bf2f(v1[j]);
            }
        }
        // reduce x-side pair (lanes differ by 8) and store scaled bf16
        #pragma unroll
        for (int j = 0; j < 32; ++j) {
            float v = acc[j];
            v += __shfl_xor(v, 8);
            acc[j] = v * sc;
        }
        if (cp == 0) {
            #pragma unroll
            for (int qv = 0; qv < 4; ++qv) {
                u16x8 ov;
                #pragma unroll
                for (int j = 0; j < 8; ++j) ov[j] = f2bf(acc[qv * 8 + j]);
                *(u16x8*)&Bt[pt][chb + qv * 64] = ov;
            }
        }
    }
    __syncthreads();

    // ---- phase C: GEMM, 8 waves x (32o x 32p), K=256, A direct from L2, no barriers ----
    int lane = tid & 63, wv = tid >> 6;
    f32x4 acc2[2][2];
    #pragma unroll
    for (int f = 0; f < 2; ++f)
        #pragma unroll
        for (int nf = 0; nf < 2; ++nf) acc2[f][nf] = (f32x4){0.f, 0.f, 0.f, 0.f};
    int arow = wv * 32 + (lane & 15);
    int kq   = (lane >> 4) * 8;
    const unsigned short* wptr = wbf + arow * 256 + kq;   // W is L2-resident (128KB)
    #pragma unroll
    for (int kt = 0; kt < 8; ++kt) {
        bf16x8 a0 = *(const bf16x8*)(wptr + kt * 32);
        bf16x8 a1 = *(const bf16x8*)(wptr + 16 * 256 + kt * 32);
        #pragma unroll
        for (int nf = 0; nf < 2; ++nf) {
            bf16x8 bb = *(const bf16x8*)&Bt[nf * 16 + (lane & 15)][kt * 32 + kq];
            acc2[0][nf] = __builtin_amdgcn_mfma_f32_16x16x32_bf16(a0, bb, acc2[0][nf], 0, 0, 0);
            acc2[1][nf] = __builtin_amdgcn_mfma_f32_16x16x32_bf16(a1, bb, acc2[1][nf], 0, 0, 0);
        }
    }
    // ---- epilogue: BN + ReLU + store ----
    #pragma unroll
    for (int f = 0; f < 2; ++f) {
        #pragma unroll
        for (int nf = 0; nf < 2; ++nf) {
            #pragma unroll
            for (int r = 0; r < 4; ++r) {
                int o = wv * 32 + f * 16 + (lane >> 4) * 4 + r;
                float y = acc2[f][nf][r] * ssb[o] + ssb[256 + o];
                out[((size_t)(b * 256 + o)) * P_TOT + pbase + nf * 16 + (lane & 15)]
                    = fmaxf(y, 0.0f);
            }
        }
    }
}

extern "C" void kernel_launch(void* const* d_in, const int* in_sizes, int n_in,
                              void* d_out, int out_size, void* d_ws, size_t ws_size,
                              hipStream_t stream) {
    const float* feats = (const float*)d_in[0];
    const float* intr  = (const float*)d_in[1];
    const float* extr  = (const float*)d_in[2];
    const float* convw = (const float*)d_in[3];
    const float* convb = (const float*)d_in[4];
    const float* gamma = (const float*)d_in[5];
    const float* beta  = (const float*)d_in[6];
    const float* mean  = (const float*)d_in[7];
    const float* var   = (const float*)d_in[8];

    char* ws = (char*)d_ws;
    float*          params = (float*)(ws + 0);              // 1152 B
    float*          sb     = (float*)(ws + 2048);           // 2 KB
    unsigned short* wbf    = (unsigned short*)(ws + 4096);  // 128 KB
    unsigned short* ft     = (unsigned short*)(ws + 135168);// 17.0 MB
    float* out = (float*)d_out;

    hipLaunchKernelGGL(prep_transpose_kernel, dim3(697), dim3(256), 0, stream,
                       feats, intr, extr, convw, convb, gamma, beta, mean, var,
                       params, sb, wbf, ft);
    hipLaunchKernelGGL(fused_kernel, dim3(1250, 4), dim3(512), 0, stream,
                       ft, params, wbf, sb, out);
}

// Round 10
// 114.455 us; speedup vs baseline: 1.5685x; 1.0077x over previous
//
#include <hip/hip_runtime.h>
#include <hip/hip_bf16.h>

// BEVFormerLite fused: project BEV grid into 6 cameras, bilinear-sample,
// average valid cams, 1x1 conv + BN + ReLU.
// B=4 N=6 C=256 fH=29 fW=50, BEV 200x200 (P=40000). Output (4,256,200,200) f32.
//
// Round 10 = r7 (best, 76.9us) + phase-B explicit 16-deep load staging.
//  r4/r5/r9 lesson: any structure that lets the compiler economize VGPRs
//  collapses gather MLP (r9: VGPR=56, 115us). Here all 16 independent corner
//  loads per slot are staged into named registers BEFORE any FMA -> one
//  latency wait per slot instead of four. ~115 VGPR, fits (512,4)'s 128 cap.

#define P_TOT  40000
#define FH     29
#define FW     50
#define NCAM   6

typedef short bf16x8 __attribute__((ext_vector_type(8)));
typedef float f32x4  __attribute__((ext_vector_type(4)));
typedef unsigned short u16x8 __attribute__((ext_vector_type(8)));

__device__ __forceinline__ float bf2f(unsigned short u) {
    union { unsigned int i; float f; } x; x.i = ((unsigned int)u) << 16; return x.f;
}
__device__ __forceinline__ unsigned short f2bf(float f) {
    union { float f; unsigned int i; } x; x.f = f;
    unsigned int i = x.i;
    return (unsigned short)((i + 0x7FFFu + ((i >> 16) & 1u)) >> 16);  // RNE
}

// ---------------- k0: transpose + W->bf16 + geometry + BN fold ----------------
__global__ __launch_bounds__(256) void prep_transpose_kernel(
        const float* __restrict__ feats, const float* __restrict__ K,
        const float* __restrict__ E, const float* __restrict__ convw,
        const float* __restrict__ convb, const float* __restrict__ gamma,
        const float* __restrict__ beta, const float* __restrict__ mean,
        const float* __restrict__ var, float* __restrict__ params,
        float* __restrict__ sb, unsigned short* __restrict__ wbf,
        unsigned short* __restrict__ ft) {
    __shared__ unsigned short tile[256][58];   // pad 50->58 (116B stride)
    int blk = blockIdx.x;
    int t   = threadIdx.x;
    if (blk < 256) {                           // W -> bf16 (65536 entries)
        int idx = blk * 256 + t;
        wbf[idx] = f2bf(convw[idx]);
    }
    if (blk == 696) {                          // geometry + BN fold
        int o = t;
        float rstd = rsqrtf(var[o] + 1e-5f);
        float s = gamma[o] * rstd;
        sb[o]       = s;
        sb[256 + o] = (convb[o] - mean[o]) * s + beta[o];
        if (o >= 24) return;
        const float* e = E + o * 16;
        const float* k = K + o * 9;
        float a00=e[0], a01=e[1], a02=e[2],  t0=e[3];
        float a10=e[4], a11=e[5], a12=e[6],  t1=e[7];
        float a20=e[8], a21=e[9], a22=e[10], t2=e[11];
        float c00 =  (a11*a22 - a12*a21);
        float c01 = -(a10*a22 - a12*a20);
        float c02 =  (a10*a21 - a11*a20);
        float det = a00*c00 + a01*c01 + a02*c02;
        float id = 1.0f / det;
        float i00 =  c00*id;
        float i01 = -(a01*a22 - a02*a21)*id;
        float i02 =  (a01*a12 - a02*a11)*id;
        float i10 =  c01*id;
        float i11 =  (a00*a22 - a02*a20)*id;
        float i12 = -(a00*a12 - a02*a10)*id;
        float i20 =  c02*id;
        float i21 = -(a00*a21 - a01*a20)*id;
        float i22 =  (a00*a11 - a01*a10)*id;
        float tp0 = -(i00*t0 + i01*t1 + i02*t2);
        float tp1 = -(i10*t0 + i11*t1 + i12*t2);
        float tp2 = -(i20*t0 + i21*t1 + i22*t2);
        float* q = params + o * 12;
        q[0] = k[0]*i00 + k[1]*i10 + k[2]*i20;
        q[1] = k[0]*i01 + k[1]*i11 + k[2]*i21;
        q[2] = k[0]*tp0 + k[1]*tp1 + k[2]*tp2;
        q[3] = k[3]*i00 + k[4]*i10 + k[5]*i20;
        q[4] = k[3]*i01 + k[4]*i11 + k[5]*i21;
        q[5] = k[3]*tp0 + k[4]*tp1 + k[5]*tp2;
        q[6] = k[6]*i00 + k[7]*i10 + k[8]*i20;
        q[7] = k[6]*i01 + k[7]*i11 + k[8]*i21;
        q[8] = k[6]*tp0 + k[7]*tp1 + k[8]*tp2;
        q[9]  = i20;
        q[10] = i21;
        q[11] = tp2;
        return;
    }
    // transpose one (bn,y) row: feats (bn,c,y,x) f32 -> ft (bn,y,x,c) bf16
    int bn = blk / FH, y = blk - bn * FH;
    const float* src = feats + (size_t)bn * 256 * FH * FW + y * FW;
    #pragma unroll
    for (int i = 0; i < 25; ++i) {             // float2 reads; pairs stay in-row (50 even)
        int flat = i * 512 + t * 2;
        int c = flat / 50;
        int x = flat - c * 50;
        float2 v = *(const float2*)(src + c * FH * FW + x);
        tile[c][x]     = f2bf(v.x);
        tile[c][x + 1] = f2bf(v.y);
    }
    __syncthreads();
    unsigned short* dst = ft + (size_t)blk * 50 * 256;
    #pragma unroll
    for (int i = 0; i < 25; ++i) {             // writes: fully coalesced u32
        int flat = i * 512 + t * 2;
        int x = flat >> 8;
        int c = flat & 255;
        unsigned int v = (unsigned int)tile[c][x] | ((unsigned int)tile[c + 1][x] << 16);
        *(unsigned int*)(dst + x * 256 + c) = v;
    }
}

// ---------------- k1: fused sample + GEMM + BN + ReLU ----------------
__global__ __launch_bounds__(512, 4) void fused_kernel(const unsigned short* __restrict__ ft,
                                                       const float* __restrict__ params,
                                                       const unsigned short* __restrict__ wbf,
                                                       const float* __restrict__ sb,
                                                       float* __restrict__ out) {
    __shared__ unsigned short Bt[64][264];        // bev tile [p][c], 528B rows
    __shared__ int           sbf[64][6];          // slot: base|okx|oky, -1 = invalid
    __shared__ unsigned int  swxy[64][6];         // wx,wy as u16 fixed-point
    __shared__ int           scnt[64];
    __shared__ float         sscale[64];
    __shared__ float         ssb[512];            // scale[256] + bias[256]

    int tid   = threadIdx.x;
    int pbase = blockIdx.x * 64;
    int b     = blockIdx.y;

    ssb[tid] = sb[tid];

    // ---- phase A: projection, one thread per (point, cam) ----
    if (tid < 384) {
        int pt  = tid / 6;
        int cam = tid - pt * 6;
        int p   = pbase + pt;
        float gx = -49.75f + 0.5f * (float)(p % 200);
        float gy = -49.75f + 0.5f * (float)(p / 200);
        const float* q = params + (b * NCAM + cam) * 12;
        float wh    = q[6] * gx + q[7]  * gy + q[8];
        float depth = q[9] * gx + q[10] * gy + q[11];
        float inv = 1.0f / (wh + 1e-6f);
        float u = (q[0] * gx + q[1] * gy + q[2]) * inv;
        float v = (q[3] * gx + q[4] * gy + q[5]) * inv;
        float un = u * (50.0f / 1600.0f) * (2.0f / 49.0f) - 1.0f;
        float vn = v * (29.0f / 928.0f)  * (2.0f / 28.0f) - 1.0f;
        int bfv = -1; unsigned int wxy = 0;
        if (depth > 0.1f && un >= -1.0f && un <= 1.0f &&
                            vn >= -1.0f && vn <= 1.0f) {
            float xs = (un + 1.0f) * 0.5f * 49.0f;
            float ys = (vn + 1.0f) * 0.5f * 28.0f;
            float x0f = floorf(xs), y0f = floorf(ys);
            float wx = xs - x0f, wy = ys - y0f;
            int x0 = (int)x0f, y0 = (int)y0f;
            int okx = (x0 < FW - 1) ? 1 : 0;
            int oky = (y0 < FH - 1) ? 2 : 0;
            int base = (((b * NCAM + cam) * FH + y0) * FW + x0) * 256; // low 8 bits free
            bfv = base | okx | oky;
            wxy = (unsigned int)(wx * 65535.0f + 0.5f)
                | ((unsigned int)(wy * 65535.0f + 0.5f) << 16);
        }
        sbf[pt][cam]  = bfv;
        swxy[pt][cam] = wxy;
    }
    __syncthreads();

    // ---- compact slots per point (cam order preserved) ----
    if (tid < 64) {
        int c = 0;
        #pragma unroll
        for (int cam = 0; cam < NCAM; ++cam) {
            int v = sbf[tid][cam];
            unsigned int w = swxy[tid][cam];
            if (v >= 0) { sbf[tid][c] = v; swxy[tid][c] = w; ++c; }
        }
        scnt[tid]   = c;
        sscale[tid] = 1.0f / ((float)c + 1e-6f);
    }
    __syncthreads();

    // ---- phase B: sample, 8 threads/point x 32 channels, 16-deep load staging ----
    {
        int pt = tid >> 3, sub = tid & 7;
        int chb = sub * 8;                       // chunk-interleaved (r7 conflict fix)
        float acc[32];
        #pragma unroll
        for (int j = 0; j < 32; ++j) acc[j] = 0.0f;
        int n = scnt[pt];
        for (int s = 0; s < n; ++s) {
            int bfv = sbf[pt][s];
            unsigned int wxy = swxy[pt][s];
            int base = bfv & ~255;
            int okx = bfv & 1, oky = bfv & 2;
            float wx = (float)(wxy & 0xffffu) * (1.0f / 65535.0f);
            float wy = (float)(wxy >> 16)     * (1.0f / 65535.0f);
            float iwx = 1.0f - wx, iwy = 1.0f - wy;
            float w00 = iwx * iwy;
            float w01 = okx ? wx * iwy : 0.0f;
            float w10 = oky ? iwx * wy : 0.0f;
            float w11 = (okx && oky) ? wx * wy : 0.0f;
            const unsigned short* p00 = ft + base + chb;
            int o01 = okx ? 256 : 0;
            int o10 = oky ? FW * 256 : 0;
            // --- stage ALL 16 independent loads first (one latency wait/slot) ---
            u16x8 v00[4], v01[4], v10[4], v11[4];
            #pragma unroll
            for (int qv = 0; qv < 4; ++qv) v00[qv] = *(const u16x8*)(p00 + qv * 64);
            #pragma unroll
            for (int qv = 0; qv < 4; ++qv) v01[qv] = *(const u16x8*)(p00 + o01 + qv * 64);
            #pragma unroll
            for (int qv = 0; qv < 4; ++qv) v10[qv] = *(const u16x8*)(p00 + o10 + qv * 64);
            #pragma unroll
            for (int qv = 0; qv < 4; ++qv) v11[qv] = *(const u16x8*)(p00 + o10 + o01 + qv * 64);
            // --- then all FMAs ---
            #pragma unroll
            for (int qv = 0; qv < 4; ++qv) {
                #pragma unroll
                for (int j = 0; j < 8; ++j) {
                    acc[qv * 8 + j] += w00 * bf2f(v00[qv][j]) + w01 * bf2f(v01[qv][j])
                                     + w10 * bf2f(v10[qv][j]) + w11 * bf2f(v11[qv][j]);
                }
            }
        }
        float sc = sscale[pt];
        #pragma unroll
        for (int qv = 0; qv < 4; ++qv) {
            u16x8 ov;
            #pragma unroll
            for (int j = 0; j < 8; ++j) ov[j] = f2bf(acc[qv * 8 + j] * sc);
            *(u16x8*)&Bt[pt][chb + qv * 64] = ov;
        }
    }
    __syncthreads();

    // ---- phase C: GEMM, 8 waves x (32o x 64p), K=256, A direct from L2, no barriers ----
    int lane = tid & 63, wv = tid >> 6;
    f32x4 acc2[2][4];
    #pragma unroll
    for (int f = 0; f < 2; ++f)
        #pragma unroll
        for (int nf = 0; nf < 4; ++nf) acc2[f][nf] = (f32x4){0.f, 0.f, 0.f, 0.f};
    int arow = wv * 32 + (lane & 15);
    int kq   = (lane >> 4) * 8;
    const unsigned short* wptr = wbf + arow * 256 + kq;   // W is L2-resident (128KB)
    #pragma unroll
    for (int kt = 0; kt < 8; ++kt) {
        bf16x8 a0 = *(const bf16x8*)(wptr + kt * 32);
        bf16x8 a1 = *(const bf16x8*)(wptr + 16 * 256 + kt * 32);
        #pragma unroll
        for (int nf = 0; nf < 4; ++nf) {
            bf16x8 bb = *(const bf16x8*)&Bt[nf * 16 + (lane & 15)][kt * 32 + kq];
            acc2[0][nf] = __builtin_amdgcn_mfma_f32_16x16x32_bf16(a0, bb, acc2[0][nf], 0, 0, 0);
            acc2[1][nf] = __builtin_amdgcn_mfma_f32_16x16x32_bf16(a1, bb, acc2[1][nf], 0, 0, 0);
        }
    }
    // ---- epilogue: BN + ReLU + store ----
    #pragma unroll
    for (int f = 0; f < 2; ++f) {
        #pragma unroll
        for (int nf = 0; nf < 4; ++nf) {
            #pragma unroll
            for (int r = 0; r < 4; ++r) {
                int o = wv * 32 + f * 16 + (lane >> 4) * 4 + r;
                float y = acc2[f][nf][r] * ssb[o] + ssb[256 + o];
                out[((size_t)(b * 256 + o)) * P_TOT + pbase + nf * 16 + (lane & 15)]
                    = fmaxf(y, 0.0f);
            }
        }
    }
}

extern "C" void kernel_launch(void* const* d_in, const int* in_sizes, int n_in,
                              void* d_out, int out_size, void* d_ws, size_t ws_size,
                              hipStream_t stream) {
    const float* feats = (const float*)d_in[0];
    const float* intr  = (const float*)d_in[1];
    const float* extr  = (const float*)d_in[2];
    const float* convw = (const float*)d_in[3];
    const float* convb = (const float*)d_in[4];
    const float* gamma = (const float*)d_in[5];
    const float* beta  = (const float*)d_in[6];
    const float* mean  = (const float*)d_in[7];
    const float* var   = (const float*)d_in[8];

    char* ws = (char*)d_ws;
    float*          params = (float*)(ws + 0);              // 1152 B
    float*          sb     = (float*)(ws + 2048);           // 2 KB
    unsigned short* wbf    = (unsigned short*)(ws + 4096);  // 128 KB
    unsigned short* ft     = (unsigned short*)(ws + 135168);// 17.0 MB
    float* out = (float*)d_out;

    hipLaunchKernelGGL(prep_transpose_kernel, dim3(697), dim3(256), 0, stream,
                       feats, intr, extr, convw, convb, gamma, beta, mean, var,
                       params, sb, wbf, ft);
    hipLaunchKernelGGL(fused_kernel, dim3(625, 4), dim3(512), 0, stream,
                       ft, params, wbf, sb, out);
}